// Round 9
// baseline (112.585 us; speedup 1.0000x reference)
//
#include <hip/hip_runtime.h>
#include <cstdint>
#include <cstddef>

typedef __attribute__((ext_vector_type(8))) _Float16 half8;
typedef __attribute__((ext_vector_type(4))) _Float16 half4;
typedef __attribute__((ext_vector_type(4))) float f32x4;

#define NB 2
#define NS 2048
#define ND 1024
#define NH 16
#define NHD 64
#define NM (NB * NS) /* 4096 */

// ---------------------------------------------------------------- prep (fused)
__device__ __forceinline__ void cvt8(const float* __restrict__ s,
                                     _Float16* __restrict__ d, int g) {
  const float4* s4 = (const float4*)s + (size_t)g * 2;
  float4 a = s4[0], b = s4[1];
  half8 h;
  h[0] = (_Float16)a.x; h[1] = (_Float16)a.y;
  h[2] = (_Float16)a.z; h[3] = (_Float16)a.w;
  h[4] = (_Float16)b.x; h[5] = (_Float16)b.y;
  h[6] = (_Float16)b.z; h[7] = (_Float16)b.w;
  *(half8*)(d + (size_t)g * 8) = h;
}

__global__ void prep(const float* __restrict__ x,
                     const float* __restrict__ wq, const float* __restrict__ wk,
                     const float* __restrict__ wv, const float* __restrict__ wo,
                     _Float16* __restrict__ xb,
                     _Float16* __restrict__ wqb, _Float16* __restrict__ wkb,
                     _Float16* __restrict__ wvb, _Float16* __restrict__ wob,
                     float* __restrict__ cosT, float* __restrict__ sinT) {
  int i = blockIdx.x * 256 + threadIdx.x;
  if (i < 524288) {
    cvt8(x, xb, i);
  } else if (i < 1048576) {
    int j = i - 524288;
    int k = j >> 17, g = j & 131071;
    const float* ws = (k == 0) ? wq : (k == 1) ? wk : (k == 2) ? wv : wo;
    _Float16* wd = (k == 0) ? wqb : (k == 1) ? wkb : (k == 2) ? wvb : wob;
    cvt8(ws, wd, g);
  } else if (i < 1056768) {
    int t0 = (i - 1048576) * 8;
#pragma unroll
    for (int e = 0; e < 8; ++e) {
      int t = t0 + e;
      int s = t >> 5, j = t & 31;
      float inv = expf(-(float)(2 * j) * (9.210340371976184f / 64.0f));
      float ang = (float)s * inv;
      cosT[t] = cosf(ang);
      sinT[t] = sinf(ang);
    }
  }
}

// ---------------------------------------------------------------- helpers
__device__ __forceinline__ void gload_lds16(const void* g, void* lds) {
  __builtin_amdgcn_global_load_lds(
      (const __attribute__((address_space(1))) unsigned int*)g,
      (__attribute__((address_space(3))) unsigned int*)lds, 16, 0, 0);
}

__device__ __forceinline__ float exp2_fast(float x) {
  float r;
  asm("v_exp_f32 %0, %1" : "=v"(r) : "v"(x));
  return r;
}

// ---------------------------------------------------------------- GEMM core
__device__ __forceinline__ void gemm_mainloop(const _Float16* __restrict__ A,
                                              const _Float16* __restrict__ Bw,
                                              _Float16* As, _Float16* Bs,
                                              int brow, int bcol,
                                              int lane, int wid,
                                              f32x4 acc[4][4]) {
  const int l15 = lane & 15, l4 = lane >> 4;
  const int wr = wid >> 1, wc = wid & 1;
  const int srow = lane >> 2, scol = (lane & 3) * 8;
  const _Float16* Ab = A + (size_t)(brow + srow) * ND + scol;
  const _Float16* Bb = Bw + (size_t)(bcol + srow) * ND + scol;

  for (int kt = 0; kt < ND / 32; ++kt) {
    const int k0 = kt * 32;
#pragma unroll
    for (int c = 0; c < 2; ++c) {
      const int chunk = wid * 2 + c;
      gload_lds16(Ab + (size_t)chunk * 16 * ND + k0, As + chunk * 512);
      gload_lds16(Bb + (size_t)chunk * 16 * ND + k0, Bs + chunk * 512);
    }
    __syncthreads();
    half8 af[4], bf[4];
#pragma unroll
    for (int m = 0; m < 4; ++m)
      af[m] = *(const half8*)(As + (wr * 64 + m * 16 + l15) * 32 + l4 * 8);
#pragma unroll
    for (int n = 0; n < 4; ++n)
      bf[n] = *(const half8*)(Bs + (wc * 64 + n * 16 + l15) * 32 + l4 * 8);
#pragma unroll
    for (int m = 0; m < 4; ++m)
#pragma unroll
      for (int n = 0; n < 4; ++n)
        acc[m][n] = __builtin_amdgcn_mfma_f32_16x16x32_f16(af[m], bf[n],
                                                           acc[m][n], 0, 0, 0);
    __syncthreads();
  }
}

// ---------------------------------------------------------------- QKV + RoPE
__launch_bounds__(256, 2)
__global__ void qkv_gemm(const _Float16* __restrict__ X,
                         const _Float16* __restrict__ Wq,
                         const _Float16* __restrict__ Wk,
                         const _Float16* __restrict__ Wv,
                         _Float16* __restrict__ Qb,
                         _Float16* __restrict__ Kb,
                         _Float16* __restrict__ Vt,
                         const float* __restrict__ cosT,
                         const float* __restrict__ sinT) {
  __shared__ __align__(16) _Float16 As[128 * 32];
  __shared__ __align__(16) _Float16 Bs[128 * 32];
  const int tid = threadIdx.x, lane = tid & 63, wid = tid >> 6;
  const int l15 = lane & 15, l4 = lane >> 4;
  const int wr = wid >> 1, wc = wid & 1;
  const int brow = blockIdx.y * 128, bcol = blockIdx.x * 128;
  const int mode = blockIdx.z;
  const _Float16* W = (mode == 0) ? Wq : (mode == 1 ? Wk : Wv);

  f32x4 acc[4][4] = {};
  gemm_mainloop(X, W, As, Bs, brow, bcol, lane, wid, acc);

  const int b = brow >> 11;
  const int sbase = (brow & (NS - 1)) + wr * 64;
  const int h = (bcol >> 6) + wc;

  if (mode < 2) {
    _Float16* oh = ((mode == 0) ? Qb : Kb) + (size_t)(b * NH + h) * NS * NHD;
#pragma unroll
    for (int m = 0; m < 4; ++m) {
#pragma unroll
      for (int r = 0; r < 4; ++r) {
        const int s = sbase + m * 16 + l4 * 4 + r;
#pragma unroll
        for (int n = 0; n < 2; ++n) {
          const int hd = n * 16 + l15;
          const float c = cosT[s * 32 + hd];
          const float sn = sinT[s * 32 + hd];
          const float lo = acc[m][n][r], hi = acc[m][n + 2][r];
          oh[(size_t)s * NHD + hd]      = (_Float16)(lo * c - hi * sn);
          oh[(size_t)s * NHD + hd + 32] = (_Float16)(hi * c + lo * sn);
        }
      }
    }
  } else {
#pragma unroll
    for (int m = 0; m < 4; ++m) {
      const int s0 = sbase + m * 16 + l4 * 4;
#pragma unroll
      for (int n = 0; n < 4; ++n) {
        const int hd = n * 16 + l15;
        half4 pk;
        pk[0] = (_Float16)acc[m][n][0];
        pk[1] = (_Float16)acc[m][n][1];
        pk[2] = (_Float16)acc[m][n][2];
        pk[3] = (_Float16)acc[m][n][3];
        *(half4*)(Vt + ((size_t)(b * NH + h) * NHD + hd) * NS + s0) = pk;
      }
    }
  }
}

// ---------------------------------------------------------------- flash attn
// In-wave software pipeline over the R6/R8 structure:
//   iter kt: stage(kt+2) | ds_read K(kt+1),V(kt) | softmax(s_cur=tile kt)
//            | QK MFMA -> s_next(tile kt+1) | pack+PV(tile kt) | vmcnt(0)+bar
// LDS-read latency hides under softmax; QK-next MFMA pipe time hides under
// pack/PV VALU. Residency: vmcnt(0) at end of iter kt drains stage(kt+2), so
// iter kt+1 may read K(kt+2). Slot (kt+2)&3 last read at iter kt-2 (PV) and
// iter kt-3 (QK-next), both >=1 barrier before the stage write.
__launch_bounds__(256, 2)
__global__ void flash_attn(const _Float16* __restrict__ Qb,
                           const _Float16* __restrict__ Kb,
                           const _Float16* __restrict__ Vt,
                           _Float16* __restrict__ Ob) {
  __shared__ __align__(16) _Float16 Ks[4][64 * 64];
  __shared__ __align__(16) _Float16 Vs[4][64 * 64];
  const int tid = threadIdx.x, lane = tid & 63, wid = tid >> 6;
  const int l15 = lane & 15, l4 = lane >> 4;
  const int bh = blockIdx.x & 31, pr = blockIdx.x >> 5;
  const _Float16* Qh = Qb + (size_t)bh * NS * NHD;
  const char* Kg = (const char*)(Kb + (size_t)bh * NS * NHD);
  const char* Vg = (const char*)(Vt + (size_t)bh * NHD * NS);

  const float K1 = 0.125f * 1.4426950408889634f;  // scale * log2(e)
  const int swz_lane = ((lane >> 3) & 7) << 4;
  const int qloc = wid * 16 + l15;
  const int rswz = (l15 & 7) << 4;
  const int b = bh >> 4, h = bh & 15;

  auto stage = [&](int kt, int si) {
#pragma unroll
    for (int c = 0; c < 2; ++c) {
      const int chunk = wid * 2 + c;
      const int slot = chunk * 1024 + lane * 16;
      const int sw = slot ^ swz_lane;
      gload_lds16(Kg + (size_t)kt * 8192 + sw, (char*)&Ks[si][0] + slot);
      const int vrow = slot >> 7;
      gload_lds16(Vg + (size_t)vrow * (NS * 2) + kt * 128 + (sw & 127),
                  (char*)&Vs[si][0] + slot);
    }
  };

  for (int item = 0; item < 2; ++item) {
    const int qt = item ? pr : 31 - pr;
    const int nkt = qt + 1;

    half8 qf[2];
#pragma unroll
    for (int kk = 0; kk < 2; ++kk)
      qf[kk] = *(const half8*)&Qh[(size_t)(qt * 64 + wid * 16 + l15) * NHD + kk * 32 + l4 * 8];

    f32x4 oacc[4] = {};
    float mrun = -3.0e38f, lrun = 0.f;

    // prologue: stage tiles 0,1; drain; compute QK of tile 0
    stage(0, 0);
    if (nkt > 1) stage(1, 1);
    asm volatile("s_waitcnt vmcnt(0)" ::: "memory");
    __builtin_amdgcn_s_barrier();
    __builtin_amdgcn_sched_barrier(0);

    f32x4 scur[4] = {};
    {
      const char* Kbuf = (const char*)&Ks[0][0];
      const bool d0 = (qt == 0);
      __builtin_amdgcn_s_setprio(1);
#pragma unroll
      for (int kk = 0; kk < 2; ++kk) {
#pragma unroll
        for (int n = 0; n < 4; ++n) {
          if (d0 && n > wid) continue;
          const int off = ((n * 16 + l15) * 128 + kk * 64 + l4 * 16) ^ rswz;
          half8 kf = *(const half8*)(Kbuf + off);
          scur[n] = __builtin_amdgcn_mfma_f32_16x16x32_f16(kf, qf[kk], scur[n], 0, 0, 0);
        }
      }
      __builtin_amdgcn_s_setprio(0);
    }

    for (int kt = 0; kt < nkt; ++kt) {
      const bool diag = (kt == qt);
      const bool havenext = (kt + 1 < nkt);
      if (kt + 2 < nkt) stage(kt + 2, (kt + 2) & 3);

      // ---- early LDS reads: K fragments of NEXT tile, V fragments of THIS
      half8 kfn[2][4];
      if (havenext) {
        const char* Kb2 = (const char*)&Ks[(kt + 1) & 3][0];
#pragma unroll
        for (int kk = 0; kk < 2; ++kk)
#pragma unroll
          for (int n = 0; n < 4; ++n) {
            const int off = ((n * 16 + l15) * 128 + kk * 64 + l4 * 16) ^ rswz;
            kfn[kk][n] = *(const half8*)(Kb2 + off);
          }
      }
      half4 vlo[2][4], vhi[2][4];
      {
        const char* Vbuf = (const char*)&Vs[kt & 3][0];
#pragma unroll
        for (int c = 0; c < 2; ++c)
#pragma unroll
          for (int n = 0; n < 4; ++n) {
            const int off0 = ((n * 16 + l15) * 128 + c * 64 + l4 * 8) ^ rswz;
            vlo[c][n] = *(const half4*)(Vbuf + off0);
            vhi[c][n] = *(const half4*)(Vbuf + (off0 ^ 32));
          }
      }

      // ---- online softmax on s_cur (tile kt) — LDS reads land underneath
      float t[16];
#pragma unroll
      for (int n = 0; n < 4; ++n)
#pragma unroll
        for (int r = 0; r < 4; ++r) {
          float v = scur[n][r] * K1;
          if (diag) {
            const int ki = n * 16 + l4 * 4 + r;
            v = (ki > qloc) ? -3.0e38f : v;
          }
          t[n * 4 + r] = v;
        }
      float mx = t[0];
#pragma unroll
      for (int j = 1; j < 16; ++j) mx = fmaxf(mx, t[j]);
      mx = fmaxf(mx, __shfl_xor(mx, 16, 64));
      mx = fmaxf(mx, __shfl_xor(mx, 32, 64));
      const float mnew = fmaxf(mrun, mx);
      const float alpha = exp2_fast(mrun - mnew);
      mrun = mnew;
      float ps[16], rs = 0.f;
#pragma unroll
      for (int j = 0; j < 16; ++j) {
        ps[j] = exp2_fast(t[j] - mnew);
        rs += ps[j];
      }
      rs += __shfl_xor(rs, 16, 64);
      rs += __shfl_xor(rs, 32, 64);
      lrun = lrun * alpha + rs;
#pragma unroll
      for (int n = 0; n < 4; ++n) {
        oacc[n][0] *= alpha; oacc[n][1] *= alpha;
        oacc[n][2] *= alpha; oacc[n][3] *= alpha;
      }

      // ---- QK of NEXT tile into s_next (operands long since resident)
      f32x4 snext[4] = {};
      if (havenext) {
        const bool dn = (kt + 1 == qt);
        __builtin_amdgcn_s_setprio(1);
#pragma unroll
        for (int kk = 0; kk < 2; ++kk)
#pragma unroll
          for (int n = 0; n < 4; ++n) {
            if (dn && n > wid) continue;
            snext[n] = __builtin_amdgcn_mfma_f32_16x16x32_f16(kfn[kk][n], qf[kk], snext[n], 0, 0, 0);
          }
        __builtin_amdgcn_s_setprio(0);
      }

      // ---- pack + PV (tile kt)
      __builtin_amdgcn_s_setprio(1);
#pragma unroll
      for (int c = 0; c < 2; ++c) {
        if (diag && c == 1 && wid < 2) continue;
        half8 pb;
#pragma unroll
        for (int j = 0; j < 8; ++j)
          pb[j] = (_Float16)ps[(2 * c + (j >> 2)) * 4 + (j & 3)];
#pragma unroll
        for (int n = 0; n < 4; ++n) {
          half8 va;
          va[0] = vlo[c][n][0]; va[1] = vlo[c][n][1];
          va[2] = vlo[c][n][2]; va[3] = vlo[c][n][3];
          va[4] = vhi[c][n][0]; va[5] = vhi[c][n][1];
          va[6] = vhi[c][n][2]; va[7] = vhi[c][n][3];
          oacc[n] = __builtin_amdgcn_mfma_f32_16x16x32_f16(va, pb, oacc[n], 0, 0, 0);
        }
      }
      __builtin_amdgcn_s_setprio(0);

      // ---- drain stages (kt+2 resident for next iter's K-next reads)
      asm volatile("s_waitcnt vmcnt(0)" ::: "memory");
      __builtin_amdgcn_s_barrier();
      __builtin_amdgcn_sched_barrier(0);

#pragma unroll
      for (int n = 0; n < 4; ++n) scur[n] = snext[n];
    }

    // ---- epilogue (registers + global only; no LDS)
    const int s = qt * 64 + wid * 16 + l15;
    const float invl = 1.0f / lrun;
#pragma unroll
    for (int n = 0; n < 4; ++n) {
      half4 o;
      o[0] = (_Float16)(oacc[n][0] * invl);
      o[1] = (_Float16)(oacc[n][1] * invl);
      o[2] = (_Float16)(oacc[n][2] * invl);
      o[3] = (_Float16)(oacc[n][3] * invl);
      *(half4*)&Ob[((size_t)(b * NS + s)) * ND + h * NHD + n * 16 + l4 * 4] = o;
    }
  }
}

// ---------------------------------------------------------------- out proj
__launch_bounds__(256, 2)
__global__ void proj_gemm(const _Float16* __restrict__ A,
                          const _Float16* __restrict__ W,
                          float* __restrict__ out) {
  __shared__ __align__(16) _Float16 As[128 * 32];
  __shared__ __align__(16) _Float16 Bs[128 * 32];
  const int tid = threadIdx.x, lane = tid & 63, wid = tid >> 6;
  const int l15 = lane & 15, l4 = lane >> 4;
  const int wr = wid >> 1, wc = wid & 1;
  const int brow = blockIdx.y * 128, bcol = blockIdx.x * 128;
  f32x4 acc[4][4] = {};
  gemm_mainloop(A, W, As, Bs, brow, bcol, lane, wid, acc);
#pragma unroll
  for (int m = 0; m < 4; ++m)
#pragma unroll
    for (int n = 0; n < 4; ++n)
#pragma unroll
      for (int r = 0; r < 4; ++r)
        out[(size_t)(brow + wr * 64 + m * 16 + l4 * 4 + r) * ND
            + bcol + wc * 64 + n * 16 + l15] = acc[m][n][r];
}

// ---------------------------------------------------------------- launch
extern "C" void kernel_launch(void* const* d_in, const int* in_sizes, int n_in,
                              void* d_out, int out_size, void* d_ws, size_t ws_size,
                              hipStream_t stream) {
  const float* x  = (const float*)d_in[0];
  const float* wq = (const float*)d_in[2];
  const float* wk = (const float*)d_in[3];
  const float* wv = (const float*)d_in[4];
  const float* wo = (const float*)d_in[5];
  float* out = (float*)d_out;

  char* w = (char*)d_ws;
  _Float16* xb   = (_Float16*)(w);                    // 8 MB  [4096][1024]
  _Float16* wqb  = (_Float16*)(w + (8ull  << 20));    // 2 MB
  _Float16* wkb  = (_Float16*)(w + (10ull << 20));
  _Float16* wvb  = (_Float16*)(w + (12ull << 20));
  _Float16* wob  = (_Float16*)(w + (14ull << 20));
  _Float16* Qb   = (_Float16*)(w + (16ull << 20));    // 8 MB  [32][2048][64]
  _Float16* Kb   = (_Float16*)(w + (24ull << 20));    // 8 MB
  _Float16* Vt   = (_Float16*)(w + (32ull << 20));    // 8 MB  [32][64][2048]
  _Float16* Ob   = (_Float16*)(w + (40ull << 20));    // 8 MB  [4096][1024]
  float*    cosT = (float*)   (w + (48ull << 20));    // 256 KB [2048][32]
  float*    sinT = (float*)   (w + (48ull << 20) + (1ull << 18));

  dim3 blk(256);
  prep<<<4128, blk, 0, stream>>>(x, wq, wk, wv, wo, xb, wqb, wkb, wvb, wob,
                                 cosT, sinT);
  qkv_gemm<<<dim3(8, 32, 3), blk, 0, stream>>>(xb, wqb, wkb, wvb, Qb, Kb, Vt,
                                               cosT, sinT);
  flash_attn<<<512, blk, 0, stream>>>(Qb, Kb, Vt, Ob);
  proj_gemm<<<dim3(8, 32), blk, 0, stream>>>(Ob, wob, out);
}

// Round 11
// 107.940 us; speedup vs baseline: 1.0430x; 1.0430x over previous
//
#include <hip/hip_runtime.h>
#include <cstdint>
#include <cstddef>

typedef __attribute__((ext_vector_type(8))) _Float16 half8;
typedef __attribute__((ext_vector_type(4))) _Float16 half4;
typedef __attribute__((ext_vector_type(2))) __fp16 fp16x2;
typedef __attribute__((ext_vector_type(4))) float f32x4;

#define NB 2
#define NS 2048
#define ND 1024
#define NH 16
#define NHD 64
#define NM (NB * NS) /* 4096 */

// ---------------------------------------------------------------- prep (fused)
__device__ __forceinline__ void cvt8(const float* __restrict__ s,
                                     _Float16* __restrict__ d, int g) {
  const float4* s4 = (const float4*)s + (size_t)g * 2;
  float4 a = s4[0], b = s4[1];
  half8 h;
  h[0] = (_Float16)a.x; h[1] = (_Float16)a.y;
  h[2] = (_Float16)a.z; h[3] = (_Float16)a.w;
  h[4] = (_Float16)b.x; h[5] = (_Float16)b.y;
  h[6] = (_Float16)b.z; h[7] = (_Float16)b.w;
  *(half8*)(d + (size_t)g * 8) = h;
}

__global__ void prep(const float* __restrict__ x,
                     const float* __restrict__ wq, const float* __restrict__ wk,
                     const float* __restrict__ wv, const float* __restrict__ wo,
                     _Float16* __restrict__ xb,
                     _Float16* __restrict__ wqb, _Float16* __restrict__ wkb,
                     _Float16* __restrict__ wvb, _Float16* __restrict__ wob,
                     float* __restrict__ cosT, float* __restrict__ sinT) {
  int i = blockIdx.x * 256 + threadIdx.x;
  if (i < 524288) {
    cvt8(x, xb, i);
  } else if (i < 1048576) {
    int j = i - 524288;
    int k = j >> 17, g = j & 131071;
    const float* ws = (k == 0) ? wq : (k == 1) ? wk : (k == 2) ? wv : wo;
    _Float16* wd = (k == 0) ? wqb : (k == 1) ? wkb : (k == 2) ? wvb : wob;
    cvt8(ws, wd, g);
  } else if (i < 1056768) {
    int t0 = (i - 1048576) * 8;
#pragma unroll
    for (int e = 0; e < 8; ++e) {
      int t = t0 + e;
      int s = t >> 5, j = t & 31;
      float inv = expf(-(float)(2 * j) * (9.210340371976184f / 64.0f));
      float ang = (float)s * inv;
      cosT[t] = cosf(ang);
      sinT[t] = sinf(ang);
    }
  }
}

// ---------------------------------------------------------------- helpers
__device__ __forceinline__ void gload_lds16(const void* g, void* lds) {
  __builtin_amdgcn_global_load_lds(
      (const __attribute__((address_space(1))) unsigned int*)g,
      (__attribute__((address_space(3))) unsigned int*)lds, 16, 0, 0);
}

__device__ __forceinline__ float exp2_fast(float x) {
  float r;
  asm("v_exp_f32 %0, %1" : "=v"(r) : "v"(x));
  return r;
}

// ---------------------------------------------------------------- GEMM core
__device__ __forceinline__ void gemm_mainloop(const _Float16* __restrict__ A,
                                              const _Float16* __restrict__ Bw,
                                              _Float16* As, _Float16* Bs,
                                              int brow, int bcol,
                                              int lane, int wid,
                                              f32x4 acc[4][4]) {
  const int l15 = lane & 15, l4 = lane >> 4;
  const int wr = wid >> 1, wc = wid & 1;
  const int srow = lane >> 2, scol = (lane & 3) * 8;
  const _Float16* Ab = A + (size_t)(brow + srow) * ND + scol;
  const _Float16* Bb = Bw + (size_t)(bcol + srow) * ND + scol;

  for (int kt = 0; kt < ND / 32; ++kt) {
    const int k0 = kt * 32;
#pragma unroll
    for (int c = 0; c < 2; ++c) {
      const int chunk = wid * 2 + c;
      gload_lds16(Ab + (size_t)chunk * 16 * ND + k0, As + chunk * 512);
      gload_lds16(Bb + (size_t)chunk * 16 * ND + k0, Bs + chunk * 512);
    }
    __syncthreads();
    half8 af[4], bf[4];
#pragma unroll
    for (int m = 0; m < 4; ++m)
      af[m] = *(const half8*)(As + (wr * 64 + m * 16 + l15) * 32 + l4 * 8);
#pragma unroll
    for (int n = 0; n < 4; ++n)
      bf[n] = *(const half8*)(Bs + (wc * 64 + n * 16 + l15) * 32 + l4 * 8);
#pragma unroll
    for (int m = 0; m < 4; ++m)
#pragma unroll
      for (int n = 0; n < 4; ++n)
        acc[m][n] = __builtin_amdgcn_mfma_f32_16x16x32_f16(af[m], bf[n],
                                                           acc[m][n], 0, 0, 0);
    __syncthreads();
  }
}

// ---------------------------------------------------------------- QKV + RoPE
__launch_bounds__(256, 2)
__global__ void qkv_gemm(const _Float16* __restrict__ X,
                         const _Float16* __restrict__ Wq,
                         const _Float16* __restrict__ Wk,
                         const _Float16* __restrict__ Wv,
                         _Float16* __restrict__ Qb,
                         _Float16* __restrict__ Kb,
                         _Float16* __restrict__ Vt,
                         const float* __restrict__ cosT,
                         const float* __restrict__ sinT) {
  __shared__ __align__(16) _Float16 As[128 * 32];
  __shared__ __align__(16) _Float16 Bs[128 * 32];
  const int tid = threadIdx.x, lane = tid & 63, wid = tid >> 6;
  const int l15 = lane & 15, l4 = lane >> 4;
  const int wr = wid >> 1, wc = wid & 1;
  const int brow = blockIdx.y * 128, bcol = blockIdx.x * 128;
  const int mode = blockIdx.z;
  const _Float16* W = (mode == 0) ? Wq : (mode == 1 ? Wk : Wv);

  f32x4 acc[4][4] = {};
  gemm_mainloop(X, W, As, Bs, brow, bcol, lane, wid, acc);

  const int b = brow >> 11;
  const int sbase = (brow & (NS - 1)) + wr * 64;
  const int h = (bcol >> 6) + wc;

  if (mode < 2) {
    _Float16* oh = ((mode == 0) ? Qb : Kb) + (size_t)(b * NH + h) * NS * NHD;
#pragma unroll
    for (int m = 0; m < 4; ++m) {
#pragma unroll
      for (int r = 0; r < 4; ++r) {
        const int s = sbase + m * 16 + l4 * 4 + r;
#pragma unroll
        for (int n = 0; n < 2; ++n) {
          const int hd = n * 16 + l15;
          const float c = cosT[s * 32 + hd];
          const float sn = sinT[s * 32 + hd];
          const float lo = acc[m][n][r], hi = acc[m][n + 2][r];
          oh[(size_t)s * NHD + hd]      = (_Float16)(lo * c - hi * sn);
          oh[(size_t)s * NHD + hd + 32] = (_Float16)(hi * c + lo * sn);
        }
      }
    }
  } else {
#pragma unroll
    for (int m = 0; m < 4; ++m) {
      const int s0 = sbase + m * 16 + l4 * 4;
#pragma unroll
      for (int n = 0; n < 4; ++n) {
        const int hd = n * 16 + l15;
        half4 pk;
        pk[0] = (_Float16)acc[m][n][0];
        pk[1] = (_Float16)acc[m][n][1];
        pk[2] = (_Float16)acc[m][n][2];
        pk[3] = (_Float16)acc[m][n][3];
        *(half4*)(Vt + ((size_t)(b * NH + h) * NHD + hd) * NS + s0) = pk;
      }
    }
  }
}

// ---------------------------------------------------------------- flash attn
// R6 skeleton (uniform sequential pair, 2-buffer LDS, __syncthreads) with
// reduced-VALU softmax: raw max -> single K1 scale; p = exp2(fma(s,K1,-m));
// cvt_pkrtz pack; vectorized alpha rescale.
__launch_bounds__(256, 4)
__global__ void flash_attn(const _Float16* __restrict__ Qb,
                           const _Float16* __restrict__ Kb,
                           const _Float16* __restrict__ Vt,
                           _Float16* __restrict__ Ob) {
  __shared__ __align__(16) _Float16 Ks[2][64 * 64];
  __shared__ __align__(16) _Float16 Vs[2][64 * 64];
  const int tid = threadIdx.x, lane = tid & 63, wid = tid >> 6;
  const int l15 = lane & 15, l4 = lane >> 4;
  const int bh = blockIdx.x & 31, pr = blockIdx.x >> 5;
  const _Float16* Qh = Qb + (size_t)bh * NS * NHD;
  const char* Kg = (const char*)(Kb + (size_t)bh * NS * NHD);
  const char* Vg = (const char*)(Vt + (size_t)bh * NHD * NS);

  const float K1 = 0.125f * 1.4426950408889634f;  // scale * log2(e)
  const int swz_lane = ((lane >> 3) & 7) << 4;
  const int qloc = wid * 16 + l15;
  const int rswz = (l15 & 7) << 4;
  const int b = bh >> 4, h = bh & 15;

  for (int item = 0; item < 2; ++item) {
    const int qt = item ? pr : 31 - pr;
    const int nkt = qt + 1;

    half8 qf[2];
#pragma unroll
    for (int kk = 0; kk < 2; ++kk)
      qf[kk] = *(const half8*)&Qh[(size_t)(qt * 64 + wid * 16 + l15) * NHD + kk * 32 + l4 * 8];

    f32x4 oacc[4] = {};
    float mrun = -3.0e38f, lrun = 0.f;

    // prologue: stage tile 0 into buf 0
#pragma unroll
    for (int c = 0; c < 2; ++c) {
      const int chunk = wid * 2 + c;
      const int slot = chunk * 1024 + lane * 16;
      const int sw = slot ^ swz_lane;
      gload_lds16(Kg + sw, (char*)&Ks[0][0] + slot);
      const int vrow = slot >> 7;
      gload_lds16(Vg + (size_t)vrow * (NS * 2) + (sw & 127), (char*)&Vs[0][0] + slot);
    }
    __syncthreads();

    int cur = 0;
    for (int kt = 0; kt < nkt; ++kt) {
      if (kt + 1 < nkt) {  // prefetch next tile into cur^1
        const size_t knext = (size_t)(kt + 1);
#pragma unroll
        for (int c = 0; c < 2; ++c) {
          const int chunk = wid * 2 + c;
          const int slot = chunk * 1024 + lane * 16;
          const int sw = slot ^ swz_lane;
          gload_lds16(Kg + knext * 8192 + sw, (char*)&Ks[cur ^ 1][0] + slot);
          const int vrow = slot >> 7;
          gload_lds16(Vg + (size_t)vrow * (NS * 2) + knext * 128 + (sw & 127),
                      (char*)&Vs[cur ^ 1][0] + slot);
        }
      }

      const bool diag = (kt == qt);
      const char* Kbuf = (const char*)&Ks[cur][0];
      const char* Vbuf = (const char*)&Vs[cur][0];

      // ---- S^T = K Q^T
      f32x4 sacc[4] = {};
      __builtin_amdgcn_s_setprio(1);
#pragma unroll
      for (int kk = 0; kk < 2; ++kk) {
#pragma unroll
        for (int n = 0; n < 4; ++n) {
          if (diag && n > wid) continue;
          const int off = ((n * 16 + l15) * 128 + kk * 64 + l4 * 16) ^ rswz;
          half8 kf = *(const half8*)(Kbuf + off);
          sacc[n] = __builtin_amdgcn_mfma_f32_16x16x32_f16(kf, qf[kk], sacc[n], 0, 0, 0);
        }
      }
      __builtin_amdgcn_s_setprio(0);

      // ---- online softmax (reduced VALU): mask raw, max raw, scale once
      float traw[16];
#pragma unroll
      for (int n = 0; n < 4; ++n)
#pragma unroll
        for (int r = 0; r < 4; ++r) {
          float v = sacc[n][r];
          if (diag) {
            const int ki = n * 16 + l4 * 4 + r;
            v = (ki > qloc) ? -3.0e38f : v;
          }
          traw[n * 4 + r] = v;
        }
      float mx = traw[0];
#pragma unroll
      for (int j = 1; j < 16; ++j) mx = fmaxf(mx, traw[j]);
      mx = fmaxf(mx, __shfl_xor(mx, 16, 64));
      mx = fmaxf(mx, __shfl_xor(mx, 32, 64));
      mx *= K1;
      const float mnew = fmaxf(mrun, mx);
      const float alpha = exp2_fast(mrun - mnew);
      mrun = mnew;
      float ps[16], rs = 0.f;
#pragma unroll
      for (int j = 0; j < 16; ++j) {
        ps[j] = exp2_fast(__builtin_fmaf(traw[j], K1, -mnew));
        rs += ps[j];
      }
      rs += __shfl_xor(rs, 16, 64);
      rs += __shfl_xor(rs, 32, 64);
      lrun = lrun * alpha + rs;
#pragma unroll
      for (int n = 0; n < 4; ++n) oacc[n] *= alpha;

      // ---- PV
      __builtin_amdgcn_s_setprio(1);
#pragma unroll
      for (int c = 0; c < 2; ++c) {
        if (diag && c == 1 && wid < 2) continue;
        half8 pb;
#pragma unroll
        for (int q2 = 0; q2 < 4; ++q2) {
          fp16x2 pp = __builtin_amdgcn_cvt_pkrtz(ps[8 * c + 2 * q2],
                                                 ps[8 * c + 2 * q2 + 1]);
          pb[2 * q2]     = (_Float16)pp[0];
          pb[2 * q2 + 1] = (_Float16)pp[1];
        }
#pragma unroll
        for (int n = 0; n < 4; ++n) {
          const int off0 = ((n * 16 + l15) * 128 + c * 64 + l4 * 8) ^ rswz;
          const int off1 = off0 ^ 32;
          half4 vlo = *(const half4*)(Vbuf + off0);
          half4 vhi = *(const half4*)(Vbuf + off1);
          half8 va;
          va[0] = vlo[0]; va[1] = vlo[1]; va[2] = vlo[2]; va[3] = vlo[3];
          va[4] = vhi[0]; va[5] = vhi[1]; va[6] = vhi[2]; va[7] = vhi[3];
          oacc[n] = __builtin_amdgcn_mfma_f32_16x16x32_f16(va, pb, oacc[n], 0, 0, 0);
        }
      }
      __builtin_amdgcn_s_setprio(0);

      __syncthreads();
      cur ^= 1;
    }

    // ---- epilogue (registers + global only; no LDS)
    const int s = qt * 64 + wid * 16 + l15;
    const float invl = 1.0f / lrun;
#pragma unroll
    for (int n = 0; n < 4; ++n) {
      f32x4 ov = oacc[n] * invl;
      half4 o;
      o[0] = (_Float16)ov[0];
      o[1] = (_Float16)ov[1];
      o[2] = (_Float16)ov[2];
      o[3] = (_Float16)ov[3];
      *(half4*)&Ob[((size_t)(b * NS + s)) * ND + h * NHD + n * 16 + l4 * 4] = o;
    }
  }
}

// ---------------------------------------------------------------- out proj
// BM=128, BN=64 tiles -> grid (16,32) = 512 blocks = 2 blocks/CU (was 1).
__launch_bounds__(256, 2)
__global__ void proj_gemm(const _Float16* __restrict__ A,
                          const _Float16* __restrict__ W,
                          float* __restrict__ out) {
  __shared__ __align__(16) _Float16 As[128 * 32];
  __shared__ __align__(16) _Float16 Bs[64 * 32];
  const int tid = threadIdx.x, lane = tid & 63, wid = tid >> 6;
  const int l15 = lane & 15, l4 = lane >> 4;
  const int wr = wid >> 1, wc = wid & 1;
  const int brow = blockIdx.y * 128, bcol = blockIdx.x * 64;
  const int srow = lane >> 2, scol = (lane & 3) * 8;
  const _Float16* Ab = A + (size_t)(brow + srow) * ND + scol;
  const _Float16* Bb = W + (size_t)(bcol + srow) * ND + scol;

  f32x4 acc[4][2] = {};
  for (int kt = 0; kt < ND / 32; ++kt) {
    const int k0 = kt * 32;
#pragma unroll
    for (int c = 0; c < 2; ++c) {
      const int chunk = wid * 2 + c;  // A rows chunk*16..+15
      gload_lds16(Ab + (size_t)chunk * 16 * ND + k0, As + chunk * 512);
    }
    gload_lds16(Bb + (size_t)wid * 16 * ND + k0, Bs + wid * 512);  // B rows wid*16..+15
    __syncthreads();
    half8 af[4], bf[2];
#pragma unroll
    for (int m = 0; m < 4; ++m)
      af[m] = *(const half8*)(As + (wr * 64 + m * 16 + l15) * 32 + l4 * 8);
#pragma unroll
    for (int n = 0; n < 2; ++n)
      bf[n] = *(const half8*)(Bs + (wc * 32 + n * 16 + l15) * 32 + l4 * 8);
#pragma unroll
    for (int m = 0; m < 4; ++m)
#pragma unroll
      for (int n = 0; n < 2; ++n)
        acc[m][n] = __builtin_amdgcn_mfma_f32_16x16x32_f16(af[m], bf[n],
                                                           acc[m][n], 0, 0, 0);
    __syncthreads();
  }
#pragma unroll
  for (int m = 0; m < 4; ++m)
#pragma unroll
    for (int n = 0; n < 2; ++n)
#pragma unroll
      for (int r = 0; r < 4; ++r)
        out[(size_t)(brow + wr * 64 + m * 16 + l4 * 4 + r) * ND
            + bcol + wc * 32 + n * 16 + l15] = acc[m][n][r];
}

// ---------------------------------------------------------------- launch
extern "C" void kernel_launch(void* const* d_in, const int* in_sizes, int n_in,
                              void* d_out, int out_size, void* d_ws, size_t ws_size,
                              hipStream_t stream) {
  const float* x  = (const float*)d_in[0];
  const float* wq = (const float*)d_in[2];
  const float* wk = (const float*)d_in[3];
  const float* wv = (const float*)d_in[4];
  const float* wo = (const float*)d_in[5];
  float* out = (float*)d_out;

  char* w = (char*)d_ws;
  _Float16* xb   = (_Float16*)(w);                    // 8 MB  [4096][1024]
  _Float16* wqb  = (_Float16*)(w + (8ull  << 20));    // 2 MB
  _Float16* wkb  = (_Float16*)(w + (10ull << 20));
  _Float16* wvb  = (_Float16*)(w + (12ull << 20));
  _Float16* wob  = (_Float16*)(w + (14ull << 20));
  _Float16* Qb   = (_Float16*)(w + (16ull << 20));    // 8 MB  [32][2048][64]
  _Float16* Kb   = (_Float16*)(w + (24ull << 20));    // 8 MB
  _Float16* Vt   = (_Float16*)(w + (32ull << 20));    // 8 MB  [32][64][2048]
  _Float16* Ob   = (_Float16*)(w + (40ull << 20));    // 8 MB  [4096][1024]
  float*    cosT = (float*)   (w + (48ull << 20));    // 256 KB [2048][32]
  float*    sinT = (float*)   (w + (48ull << 20) + (1ull << 18));

  dim3 blk(256);
  prep<<<4128, blk, 0, stream>>>(x, wq, wk, wv, wo, xb, wqb, wkb, wvb, wob,
                                 cosT, sinT);
  qkv_gemm<<<dim3(8, 32, 3), blk, 0, stream>>>(xb, wqb, wkb, wvb, Qb, Kb, Vt,
                                               cosT, sinT);
  flash_attn<<<512, blk, 0, stream>>>(Qb, Kb, Vt, Ob);
  proj_gemm<<<dim3(16, 32), blk, 0, stream>>>(Ob, wob, out);
}

// Round 12
// 100.374 us; speedup vs baseline: 1.1216x; 1.0754x over previous
//
#include <hip/hip_runtime.h>
#include <cstdint>
#include <cstddef>

typedef __attribute__((ext_vector_type(8))) _Float16 half8;
typedef __attribute__((ext_vector_type(4))) _Float16 half4;
typedef __attribute__((ext_vector_type(2))) __fp16 fp16x2;
typedef __attribute__((ext_vector_type(4))) float f32x4;

#define NB 2
#define NS 2048
#define ND 1024
#define NH 16
#define NHD 64
#define NM (NB * NS) /* 4096 */

// ---------------------------------------------------------------- prep (fused)
__device__ __forceinline__ void cvt8(const float* __restrict__ s,
                                     _Float16* __restrict__ d, int g) {
  const float4* s4 = (const float4*)s + (size_t)g * 2;
  float4 a = s4[0], b = s4[1];
  half8 h;
  h[0] = (_Float16)a.x; h[1] = (_Float16)a.y;
  h[2] = (_Float16)a.z; h[3] = (_Float16)a.w;
  h[4] = (_Float16)b.x; h[5] = (_Float16)b.y;
  h[6] = (_Float16)b.z; h[7] = (_Float16)b.w;
  *(half8*)(d + (size_t)g * 8) = h;
}

__global__ void prep(const float* __restrict__ x,
                     const float* __restrict__ wq, const float* __restrict__ wk,
                     const float* __restrict__ wv, const float* __restrict__ wo,
                     _Float16* __restrict__ xb,
                     _Float16* __restrict__ wqb, _Float16* __restrict__ wkb,
                     _Float16* __restrict__ wvb, _Float16* __restrict__ wob,
                     float* __restrict__ cosT, float* __restrict__ sinT) {
  int i = blockIdx.x * 256 + threadIdx.x;
  if (i < 524288) {
    cvt8(x, xb, i);
  } else if (i < 1048576) {
    int j = i - 524288;
    int k = j >> 17, g = j & 131071;
    const float* ws = (k == 0) ? wq : (k == 1) ? wk : (k == 2) ? wv : wo;
    _Float16* wd = (k == 0) ? wqb : (k == 1) ? wkb : (k == 2) ? wvb : wob;
    cvt8(ws, wd, g);
  } else if (i < 1056768) {
    int t0 = (i - 1048576) * 8;
#pragma unroll
    for (int e = 0; e < 8; ++e) {
      int t = t0 + e;
      int s = t >> 5, j = t & 31;
      float inv = expf(-(float)(2 * j) * (9.210340371976184f / 64.0f));
      float ang = (float)s * inv;
      cosT[t] = cosf(ang);
      sinT[t] = sinf(ang);
    }
  }
}

// ---------------------------------------------------------------- helpers
__device__ __forceinline__ void gload_lds16(const void* g, void* lds) {
  __builtin_amdgcn_global_load_lds(
      (const __attribute__((address_space(1))) unsigned int*)g,
      (__attribute__((address_space(3))) unsigned int*)lds, 16, 0, 0);
}

__device__ __forceinline__ float exp2_fast(float x) {
  float r;
  asm("v_exp_f32 %0, %1" : "=v"(r) : "v"(x));
  return r;
}

// ---------------------------------------------------------------- GEMM core
// BK=64 mainloop: tiles [rows][64] f16, row stride 128B, XOR-swizzled
// (byte ^ (row&7)<<4) with pre-swizzled global source. 16 K-iters, 2 kk each.
__device__ __forceinline__ void gemm_mainloop64(const _Float16* __restrict__ A,
                                                const _Float16* __restrict__ Bw,
                                                _Float16* As, _Float16* Bs,
                                                int brow, int bcol,
                                                int lane, int wid, int tid,
                                                f32x4 acc[4][4]) {
  const int l15 = lane & 15, l4 = lane >> 4;
  const int wr = wid >> 1, wc = wid & 1;
  const int rswz = (l15 & 7) << 4;
  const int srb = tid >> 3;            // staging row base (0..31)
  const int scb = (tid & 7) * 16;      // staging col byte

  for (int kt = 0; kt < ND / 64; ++kt) {
    const int k0 = kt * 64;
#pragma unroll
    for (int c = 0; c < 4; ++c) {
      const int r = c * 32 + srb;
      const int sb = scb ^ ((r & 7) << 4);   // pre-swizzled source col
      gload_lds16((const char*)(A + (size_t)(brow + r) * ND + k0) + sb,
                  (char*)As + c * 4096 + tid * 16);
      gload_lds16((const char*)(Bw + (size_t)(bcol + r) * ND + k0) + sb,
                  (char*)Bs + c * 4096 + tid * 16);
    }
    __syncthreads();
#pragma unroll
    for (int kk = 0; kk < 2; ++kk) {
      half8 af[4], bf[4];
#pragma unroll
      for (int m = 0; m < 4; ++m) {
        const int row = wr * 64 + m * 16 + l15;
        af[m] = *(const half8*)((const char*)As +
                 ((row * 128 + kk * 64 + l4 * 16) ^ rswz));
      }
#pragma unroll
      for (int n = 0; n < 4; ++n) {
        const int row = wc * 64 + n * 16 + l15;
        bf[n] = *(const half8*)((const char*)Bs +
                 ((row * 128 + kk * 64 + l4 * 16) ^ rswz));
      }
#pragma unroll
      for (int m = 0; m < 4; ++m)
#pragma unroll
        for (int n = 0; n < 4; ++n)
          acc[m][n] = __builtin_amdgcn_mfma_f32_16x16x32_f16(af[m], bf[n],
                                                             acc[m][n], 0, 0, 0);
    }
    __syncthreads();
  }
}

// ---------------------------------------------------------------- QKV + RoPE
__launch_bounds__(256, 2)
__global__ void qkv_gemm(const _Float16* __restrict__ X,
                         const _Float16* __restrict__ Wq,
                         const _Float16* __restrict__ Wk,
                         const _Float16* __restrict__ Wv,
                         _Float16* __restrict__ Qb,
                         _Float16* __restrict__ Kb,
                         _Float16* __restrict__ Vt,
                         const float* __restrict__ cosT,
                         const float* __restrict__ sinT) {
  __shared__ __align__(16) _Float16 As[128 * 64];
  __shared__ __align__(16) _Float16 Bs[128 * 64];
  const int tid = threadIdx.x, lane = tid & 63, wid = tid >> 6;
  const int l15 = lane & 15, l4 = lane >> 4;
  const int wr = wid >> 1, wc = wid & 1;
  const int brow = blockIdx.y * 128, bcol = blockIdx.x * 128;
  const int mode = blockIdx.z;
  const _Float16* W = (mode == 0) ? Wq : (mode == 1 ? Wk : Wv);

  f32x4 acc[4][4] = {};
  gemm_mainloop64(X, W, As, Bs, brow, bcol, lane, wid, tid, acc);

  const int b = brow >> 11;
  const int sbase = (brow & (NS - 1)) + wr * 64;
  const int h = (bcol >> 6) + wc;

  if (mode < 2) {
    _Float16* oh = ((mode == 0) ? Qb : Kb) + (size_t)(b * NH + h) * NS * NHD;
#pragma unroll
    for (int m = 0; m < 4; ++m) {
#pragma unroll
      for (int r = 0; r < 4; ++r) {
        const int s = sbase + m * 16 + l4 * 4 + r;
#pragma unroll
        for (int n = 0; n < 2; ++n) {
          const int hd = n * 16 + l15;
          const float c = cosT[s * 32 + hd];
          const float sn = sinT[s * 32 + hd];
          const float lo = acc[m][n][r], hi = acc[m][n + 2][r];
          oh[(size_t)s * NHD + hd]      = (_Float16)(lo * c - hi * sn);
          oh[(size_t)s * NHD + hd + 32] = (_Float16)(hi * c + lo * sn);
        }
      }
    }
  } else {
    // V stored transposed AND k-interleaved within each 64-key tile:
    // tile-local newpos = (m>>1)*32 + l4*8 + (m&1)*4  (pairs k and k+16 adjacent)
#pragma unroll
    for (int m = 0; m < 4; ++m) {
      const int s0 = sbase + m * 16 + l4 * 4;
      const int npos = (s0 & ~63) + (m >> 1) * 32 + l4 * 8 + (m & 1) * 4;
#pragma unroll
      for (int n = 0; n < 4; ++n) {
        const int hd = n * 16 + l15;
        half4 pk;
        pk[0] = (_Float16)acc[m][n][0];
        pk[1] = (_Float16)acc[m][n][1];
        pk[2] = (_Float16)acc[m][n][2];
        pk[3] = (_Float16)acc[m][n][3];
        *(half4*)(Vt + ((size_t)(b * NH + h) * NHD + hd) * NS + npos) = pk;
      }
    }
  }
}

// ---------------------------------------------------------------- flash attn
// R11 skeleton; PV now reads V as ONE b128 per (c,n) (V k-interleaved in
// global) with the same swizzled address form as the K reads.
__launch_bounds__(256, 4)
__global__ void flash_attn(const _Float16* __restrict__ Qb,
                           const _Float16* __restrict__ Kb,
                           const _Float16* __restrict__ Vt,
                           _Float16* __restrict__ Ob) {
  __shared__ __align__(16) _Float16 Ks[2][64 * 64];
  __shared__ __align__(16) _Float16 Vs[2][64 * 64];
  const int tid = threadIdx.x, lane = tid & 63, wid = tid >> 6;
  const int l15 = lane & 15, l4 = lane >> 4;
  const int bh = blockIdx.x & 31, pr = blockIdx.x >> 5;
  const _Float16* Qh = Qb + (size_t)bh * NS * NHD;
  const char* Kg = (const char*)(Kb + (size_t)bh * NS * NHD);
  const char* Vg = (const char*)(Vt + (size_t)bh * NHD * NS);

  const float K1 = 0.125f * 1.4426950408889634f;  // scale * log2(e)
  const int swz_lane = ((lane >> 3) & 7) << 4;
  const int qloc = wid * 16 + l15;
  const int rswz = (l15 & 7) << 4;
  const int b = bh >> 4, h = bh & 15;

  for (int item = 0; item < 2; ++item) {
    const int qt = item ? pr : 31 - pr;
    const int nkt = qt + 1;

    half8 qf[2];
#pragma unroll
    for (int kk = 0; kk < 2; ++kk)
      qf[kk] = *(const half8*)&Qh[(size_t)(qt * 64 + wid * 16 + l15) * NHD + kk * 32 + l4 * 8];

    f32x4 oacc[4] = {};
    float mrun = -3.0e38f, lrun = 0.f;

    // prologue: stage tile 0 into buf 0
#pragma unroll
    for (int c = 0; c < 2; ++c) {
      const int chunk = wid * 2 + c;
      const int slot = chunk * 1024 + lane * 16;
      const int sw = slot ^ swz_lane;
      gload_lds16(Kg + sw, (char*)&Ks[0][0] + slot);
      const int vrow = slot >> 7;
      gload_lds16(Vg + (size_t)vrow * (NS * 2) + (sw & 127), (char*)&Vs[0][0] + slot);
    }
    __syncthreads();

    int cur = 0;
    for (int kt = 0; kt < nkt; ++kt) {
      if (kt + 1 < nkt) {  // prefetch next tile into cur^1
        const size_t knext = (size_t)(kt + 1);
#pragma unroll
        for (int c = 0; c < 2; ++c) {
          const int chunk = wid * 2 + c;
          const int slot = chunk * 1024 + lane * 16;
          const int sw = slot ^ swz_lane;
          gload_lds16(Kg + knext * 8192 + sw, (char*)&Ks[cur ^ 1][0] + slot);
          const int vrow = slot >> 7;
          gload_lds16(Vg + (size_t)vrow * (NS * 2) + knext * 128 + (sw & 127),
                      (char*)&Vs[cur ^ 1][0] + slot);
        }
      }

      const bool diag = (kt == qt);
      const char* Kbuf = (const char*)&Ks[cur][0];
      const char* Vbuf = (const char*)&Vs[cur][0];

      // ---- S^T = K Q^T
      f32x4 sacc[4] = {};
      __builtin_amdgcn_s_setprio(1);
#pragma unroll
      for (int kk = 0; kk < 2; ++kk) {
#pragma unroll
        for (int n = 0; n < 4; ++n) {
          if (diag && n > wid) continue;
          const int off = ((n * 16 + l15) * 128 + kk * 64 + l4 * 16) ^ rswz;
          half8 kf = *(const half8*)(Kbuf + off);
          sacc[n] = __builtin_amdgcn_mfma_f32_16x16x32_f16(kf, qf[kk], sacc[n], 0, 0, 0);
        }
      }
      __builtin_amdgcn_s_setprio(0);

      // ---- online softmax (reduced VALU)
      float traw[16];
#pragma unroll
      for (int n = 0; n < 4; ++n)
#pragma unroll
        for (int r = 0; r < 4; ++r) {
          float v = sacc[n][r];
          if (diag) {
            const int ki = n * 16 + l4 * 4 + r;
            v = (ki > qloc) ? -3.0e38f : v;
          }
          traw[n * 4 + r] = v;
        }
      float mx = traw[0];
#pragma unroll
      for (int j = 1; j < 16; ++j) mx = fmaxf(mx, traw[j]);
      mx = fmaxf(mx, __shfl_xor(mx, 16, 64));
      mx = fmaxf(mx, __shfl_xor(mx, 32, 64));
      mx *= K1;
      const float mnew = fmaxf(mrun, mx);
      const float alpha = exp2_fast(mrun - mnew);
      mrun = mnew;
      float ps[16], rs = 0.f;
#pragma unroll
      for (int j = 0; j < 16; ++j) {
        ps[j] = exp2_fast(__builtin_fmaf(traw[j], K1, -mnew));
        rs += ps[j];
      }
      rs += __shfl_xor(rs, 16, 64);
      rs += __shfl_xor(rs, 32, 64);
      lrun = lrun * alpha + rs;
#pragma unroll
      for (int n = 0; n < 4; ++n) oacc[n] *= alpha;

      // ---- PV (V k-interleaved: one b128 per (c,n))
      __builtin_amdgcn_s_setprio(1);
#pragma unroll
      for (int c = 0; c < 2; ++c) {
        if (diag && c == 1 && wid < 2) continue;
        half8 pb;
#pragma unroll
        for (int q2 = 0; q2 < 4; ++q2) {
          fp16x2 pp = __builtin_amdgcn_cvt_pkrtz(ps[8 * c + 2 * q2],
                                                 ps[8 * c + 2 * q2 + 1]);
          pb[2 * q2]     = (_Float16)pp[0];
          pb[2 * q2 + 1] = (_Float16)pp[1];
        }
#pragma unroll
        for (int n = 0; n < 4; ++n) {
          const int off = ((n * 16 + l15) * 128 + c * 64 + l4 * 16) ^ rswz;
          half8 va = *(const half8*)(Vbuf + off);
          oacc[n] = __builtin_amdgcn_mfma_f32_16x16x32_f16(va, pb, oacc[n], 0, 0, 0);
        }
      }
      __builtin_amdgcn_s_setprio(0);

      __syncthreads();
      cur ^= 1;
    }

    // ---- epilogue (registers + global only; no LDS)
    const int s = qt * 64 + wid * 16 + l15;
    const float invl = 1.0f / lrun;
#pragma unroll
    for (int n = 0; n < 4; ++n) {
      f32x4 ov = oacc[n] * invl;
      half4 o;
      o[0] = (_Float16)ov[0];
      o[1] = (_Float16)ov[1];
      o[2] = (_Float16)ov[2];
      o[3] = (_Float16)ov[3];
      *(half4*)&Ob[((size_t)(b * NS + s)) * ND + h * NHD + n * 16 + l4 * 4] = o;
    }
  }
}

// ---------------------------------------------------------------- out proj
// BM=128, BN=64, BK=64 (swizzled). Grid (16,32) = 512 blocks.
__launch_bounds__(256, 2)
__global__ void proj_gemm(const _Float16* __restrict__ A,
                          const _Float16* __restrict__ W,
                          float* __restrict__ out) {
  __shared__ __align__(16) _Float16 As[128 * 64];
  __shared__ __align__(16) _Float16 Bs[64 * 64];
  const int tid = threadIdx.x, lane = tid & 63, wid = tid >> 6;
  const int l15 = lane & 15, l4 = lane >> 4;
  const int wr = wid >> 1, wc = wid & 1;
  const int brow = blockIdx.y * 128, bcol = blockIdx.x * 64;
  const int rswz = (l15 & 7) << 4;
  const int srb = tid >> 3;
  const int scb = (tid & 7) * 16;

  f32x4 acc[4][2] = {};
  for (int kt = 0; kt < ND / 64; ++kt) {
    const int k0 = kt * 64;
#pragma unroll
    for (int c = 0; c < 4; ++c) {
      const int r = c * 32 + srb;
      const int sb = scb ^ ((r & 7) << 4);
      gload_lds16((const char*)(A + (size_t)(brow + r) * ND + k0) + sb,
                  (char*)As + c * 4096 + tid * 16);
    }
#pragma unroll
    for (int c = 0; c < 2; ++c) {
      const int r = c * 32 + srb;
      const int sb = scb ^ ((r & 7) << 4);
      gload_lds16((const char*)(W + (size_t)(bcol + r) * ND + k0) + sb,
                  (char*)Bs + c * 4096 + tid * 16);
    }
    __syncthreads();
#pragma unroll
    for (int kk = 0; kk < 2; ++kk) {
      half8 af[4], bf[2];
#pragma unroll
      for (int m = 0; m < 4; ++m) {
        const int row = wr * 64 + m * 16 + l15;
        af[m] = *(const half8*)((const char*)As +
                 ((row * 128 + kk * 64 + l4 * 16) ^ rswz));
      }
#pragma unroll
      for (int n = 0; n < 2; ++n) {
        const int row = wc * 32 + n * 16 + l15;
        bf[n] = *(const half8*)((const char*)Bs +
                 ((row * 128 + kk * 64 + l4 * 16) ^ rswz));
      }
#pragma unroll
      for (int m = 0; m < 4; ++m)
#pragma unroll
        for (int n = 0; n < 2; ++n)
          acc[m][n] = __builtin_amdgcn_mfma_f32_16x16x32_f16(af[m], bf[n],
                                                             acc[m][n], 0, 0, 0);
    }
    __syncthreads();
  }
#pragma unroll
  for (int m = 0; m < 4; ++m)
#pragma unroll
    for (int n = 0; n < 2; ++n)
#pragma unroll
      for (int r = 0; r < 4; ++r)
        out[(size_t)(brow + wr * 64 + m * 16 + l4 * 4 + r) * ND
            + bcol + wc * 32 + n * 16 + l15] = acc[m][n][r];
}

// ---------------------------------------------------------------- launch
extern "C" void kernel_launch(void* const* d_in, const int* in_sizes, int n_in,
                              void* d_out, int out_size, void* d_ws, size_t ws_size,
                              hipStream_t stream) {
  const float* x  = (const float*)d_in[0];
  const float* wq = (const float*)d_in[2];
  const float* wk = (const float*)d_in[3];
  const float* wv = (const float*)d_in[4];
  const float* wo = (const float*)d_in[5];
  float* out = (float*)d_out;

  char* w = (char*)d_ws;
  _Float16* xb   = (_Float16*)(w);                    // 8 MB  [4096][1024]
  _Float16* wqb  = (_Float16*)(w + (8ull  << 20));    // 2 MB
  _Float16* wkb  = (_Float16*)(w + (10ull << 20));
  _Float16* wvb  = (_Float16*)(w + (12ull << 20));
  _Float16* wob  = (_Float16*)(w + (14ull << 20));
  _Float16* Qb   = (_Float16*)(w + (16ull << 20));    // 8 MB  [32][2048][64]
  _Float16* Kb   = (_Float16*)(w + (24ull << 20));    // 8 MB
  _Float16* Vt   = (_Float16*)(w + (32ull << 20));    // 8 MB  [32][64][2048] (k-interleaved)
  _Float16* Ob   = (_Float16*)(w + (40ull << 20));    // 8 MB  [4096][1024]
  float*    cosT = (float*)   (w + (48ull << 20));    // 256 KB [2048][32]
  float*    sinT = (float*)   (w + (48ull << 20) + (1ull << 18));

  dim3 blk(256);
  prep<<<4128, blk, 0, stream>>>(x, wq, wk, wv, wo, xb, wqb, wkb, wvb, wob,
                                 cosT, sinT);
  qkv_gemm<<<dim3(8, 32, 3), blk, 0, stream>>>(xb, wqb, wkb, wvb, Qb, Kb, Vt,
                                               cosT, sinT);
  flash_attn<<<512, blk, 0, stream>>>(Qb, Kb, Vt, Ob);
  proj_gemm<<<dim3(16, 32), blk, 0, stream>>>(Ob, wob, out);
}

// Round 13
// 99.929 us; speedup vs baseline: 1.1267x; 1.0045x over previous
//
#include <hip/hip_runtime.h>
#include <cstdint>
#include <cstddef>

typedef __attribute__((ext_vector_type(8))) _Float16 half8;
typedef __attribute__((ext_vector_type(4))) _Float16 half4;
typedef __attribute__((ext_vector_type(2))) __fp16 fp16x2;
typedef __attribute__((ext_vector_type(4))) float f32x4;

#define NB 2
#define NS 2048
#define ND 1024
#define NH 16
#define NHD 64
#define NM (NB * NS) /* 4096 */

// ---------------------------------------------------------------- prep (fused)
__device__ __forceinline__ void cvt8(const float* __restrict__ s,
                                     _Float16* __restrict__ d, int g) {
  const float4* s4 = (const float4*)s + (size_t)g * 2;
  float4 a = s4[0], b = s4[1];
  half8 h;
  h[0] = (_Float16)a.x; h[1] = (_Float16)a.y;
  h[2] = (_Float16)a.z; h[3] = (_Float16)a.w;
  h[4] = (_Float16)b.x; h[5] = (_Float16)b.y;
  h[6] = (_Float16)b.z; h[7] = (_Float16)b.w;
  *(half8*)(d + (size_t)g * 8) = h;
}

__global__ void prep(const float* __restrict__ x,
                     const float* __restrict__ wq, const float* __restrict__ wk,
                     const float* __restrict__ wv, const float* __restrict__ wo,
                     _Float16* __restrict__ xb,
                     _Float16* __restrict__ wqb, _Float16* __restrict__ wkb,
                     _Float16* __restrict__ wvb, _Float16* __restrict__ wob,
                     float* __restrict__ cosT, float* __restrict__ sinT) {
  int i = blockIdx.x * 256 + threadIdx.x;
  if (i < 524288) {
    cvt8(x, xb, i);
  } else if (i < 1048576) {
    int j = i - 524288;
    int k = j >> 17, g = j & 131071;
    const float* ws = (k == 0) ? wq : (k == 1) ? wk : (k == 2) ? wv : wo;
    _Float16* wd = (k == 0) ? wqb : (k == 1) ? wkb : (k == 2) ? wvb : wob;
    cvt8(ws, wd, g);
  } else if (i < 1056768) {
    int t0 = (i - 1048576) * 8;
#pragma unroll
    for (int e = 0; e < 8; ++e) {
      int t = t0 + e;
      int s = t >> 5, j = t & 31;
      float inv = expf(-(float)(2 * j) * (9.210340371976184f / 64.0f));
      float ang = (float)s * inv;
      cosT[t] = cosf(ang);
      sinT[t] = sinf(ang);
    }
  }
}

// ---------------------------------------------------------------- helpers
__device__ __forceinline__ void gload_lds16(const void* g, void* lds) {
  __builtin_amdgcn_global_load_lds(
      (const __attribute__((address_space(1))) unsigned int*)g,
      (__attribute__((address_space(3))) unsigned int*)lds, 16, 0, 0);
}

__device__ __forceinline__ float exp2_fast(float x) {
  float r;
  asm("v_exp_f32 %0, %1" : "=v"(r) : "v"(x));
  return r;
}

// ---------------------------------------------------------------- GEMM core
// BK=64 mainloop: tiles [rows][64] f16, row stride 128B, XOR-swizzled
// (byte ^ (row&7)<<4) with pre-swizzled global source. 16 K-iters, 2 kk each.
__device__ __forceinline__ void gemm_mainloop64(const _Float16* __restrict__ A,
                                                const _Float16* __restrict__ Bw,
                                                _Float16* As, _Float16* Bs,
                                                int brow, int bcol,
                                                int lane, int wid, int tid,
                                                f32x4 acc[4][4]) {
  const int l15 = lane & 15, l4 = lane >> 4;
  const int wr = wid >> 1, wc = wid & 1;
  const int rswz = (l15 & 7) << 4;
  const int srb = tid >> 3;            // staging row base (0..31)
  const int scb = (tid & 7) * 16;      // staging col byte

  for (int kt = 0; kt < ND / 64; ++kt) {
    const int k0 = kt * 64;
#pragma unroll
    for (int c = 0; c < 4; ++c) {
      const int r = c * 32 + srb;
      const int sb = scb ^ ((r & 7) << 4);   // pre-swizzled source col
      gload_lds16((const char*)(A + (size_t)(brow + r) * ND + k0) + sb,
                  (char*)As + c * 4096 + tid * 16);
      gload_lds16((const char*)(Bw + (size_t)(bcol + r) * ND + k0) + sb,
                  (char*)Bs + c * 4096 + tid * 16);
    }
    __syncthreads();
#pragma unroll
    for (int kk = 0; kk < 2; ++kk) {
      half8 af[4], bf[4];
#pragma unroll
      for (int m = 0; m < 4; ++m) {
        const int row = wr * 64 + m * 16 + l15;
        af[m] = *(const half8*)((const char*)As +
                 ((row * 128 + kk * 64 + l4 * 16) ^ rswz));
      }
#pragma unroll
      for (int n = 0; n < 4; ++n) {
        const int row = wc * 64 + n * 16 + l15;
        bf[n] = *(const half8*)((const char*)Bs +
                 ((row * 128 + kk * 64 + l4 * 16) ^ rswz));
      }
#pragma unroll
      for (int m = 0; m < 4; ++m)
#pragma unroll
        for (int n = 0; n < 4; ++n)
          acc[m][n] = __builtin_amdgcn_mfma_f32_16x16x32_f16(af[m], bf[n],
                                                             acc[m][n], 0, 0, 0);
    }
    __syncthreads();
  }
}

// ---------------------------------------------------------------- QKV + RoPE
__launch_bounds__(256, 2)
__global__ void qkv_gemm(const _Float16* __restrict__ X,
                         const _Float16* __restrict__ Wq,
                         const _Float16* __restrict__ Wk,
                         const _Float16* __restrict__ Wv,
                         _Float16* __restrict__ Qb,
                         _Float16* __restrict__ Kb,
                         _Float16* __restrict__ Vt,
                         const float* __restrict__ cosT,
                         const float* __restrict__ sinT) {
  __shared__ __align__(16) _Float16 As[128 * 64];
  __shared__ __align__(16) _Float16 Bs[128 * 64];
  const int tid = threadIdx.x, lane = tid & 63, wid = tid >> 6;
  const int l15 = lane & 15, l4 = lane >> 4;
  const int wr = wid >> 1, wc = wid & 1;
  const int brow = blockIdx.y * 128, bcol = blockIdx.x * 128;
  const int mode = blockIdx.z;
  const _Float16* W = (mode == 0) ? Wq : (mode == 1 ? Wk : Wv);

  f32x4 acc[4][4] = {};
  gemm_mainloop64(X, W, As, Bs, brow, bcol, lane, wid, tid, acc);

  const int b = brow >> 11;
  const int sbase = (brow & (NS - 1)) + wr * 64;
  const int h = (bcol >> 6) + wc;

  if (mode < 2) {
    _Float16* oh = ((mode == 0) ? Qb : Kb) + (size_t)(b * NH + h) * NS * NHD;
#pragma unroll
    for (int m = 0; m < 4; ++m) {
#pragma unroll
      for (int r = 0; r < 4; ++r) {
        const int s = sbase + m * 16 + l4 * 4 + r;
#pragma unroll
        for (int n = 0; n < 2; ++n) {
          const int hd = n * 16 + l15;
          const float c = cosT[s * 32 + hd];
          const float sn = sinT[s * 32 + hd];
          const float lo = acc[m][n][r], hi = acc[m][n + 2][r];
          oh[(size_t)s * NHD + hd]      = (_Float16)(lo * c - hi * sn);
          oh[(size_t)s * NHD + hd + 32] = (_Float16)(hi * c + lo * sn);
        }
      }
    }
  } else {
    // V stored transposed AND k-interleaved within each 64-key tile:
    // tile-local newpos = (m>>1)*32 + l4*8 + (m&1)*4  (pairs k and k+16 adjacent)
#pragma unroll
    for (int m = 0; m < 4; ++m) {
      const int s0 = sbase + m * 16 + l4 * 4;
      const int npos = (s0 & ~63) + (m >> 1) * 32 + l4 * 8 + (m & 1) * 4;
#pragma unroll
      for (int n = 0; n < 4; ++n) {
        const int hd = n * 16 + l15;
        half4 pk;
        pk[0] = (_Float16)acc[m][n][0];
        pk[1] = (_Float16)acc[m][n][1];
        pk[2] = (_Float16)acc[m][n][2];
        pk[3] = (_Float16)acc[m][n][3];
        *(half4*)(Vt + ((size_t)(b * NH + h) * NHD + hd) * NS + npos) = pk;
      }
    }
  }
}

// ---------------------------------------------------------------- flash attn
// One q-tile per block, grid 1024, LONGEST-FIRST dispatch (qt = 31 - bid>>5):
// long blocks launch first, short blocks pack the tail. 4 blocks/CU
// (32KB LDS, 56 VGPR) -> 4 waves/SIMD hide the softmax dependency chain.
// Per-iter body identical to R12 (conflict-free K/V b128 reads).
__launch_bounds__(256, 4)
__global__ void flash_attn(const _Float16* __restrict__ Qb,
                           const _Float16* __restrict__ Kb,
                           const _Float16* __restrict__ Vt,
                           _Float16* __restrict__ Ob) {
  __shared__ __align__(16) _Float16 Ks[2][64 * 64];
  __shared__ __align__(16) _Float16 Vs[2][64 * 64];
  const int tid = threadIdx.x, lane = tid & 63, wid = tid >> 6;
  const int l15 = lane & 15, l4 = lane >> 4;
  const int bh = blockIdx.x & 31;
  const int qt = 31 - (blockIdx.x >> 5);
  const _Float16* Qh = Qb + (size_t)bh * NS * NHD;
  const char* Kg = (const char*)(Kb + (size_t)bh * NS * NHD);
  const char* Vg = (const char*)(Vt + (size_t)bh * NHD * NS);

  const float K1 = 0.125f * 1.4426950408889634f;  // scale * log2(e)
  const int swz_lane = ((lane >> 3) & 7) << 4;
  const int qloc = wid * 16 + l15;
  const int rswz = (l15 & 7) << 4;
  const int b = bh >> 4, h = bh & 15;
  const int nkt = qt + 1;

  half8 qf[2];
#pragma unroll
  for (int kk = 0; kk < 2; ++kk)
    qf[kk] = *(const half8*)&Qh[(size_t)(qt * 64 + wid * 16 + l15) * NHD + kk * 32 + l4 * 8];

  f32x4 oacc[4] = {};
  float mrun = -3.0e38f, lrun = 0.f;

  // prologue: stage tile 0 into buf 0
#pragma unroll
  for (int c = 0; c < 2; ++c) {
    const int chunk = wid * 2 + c;
    const int slot = chunk * 1024 + lane * 16;
    const int sw = slot ^ swz_lane;
    gload_lds16(Kg + sw, (char*)&Ks[0][0] + slot);
    const int vrow = slot >> 7;
    gload_lds16(Vg + (size_t)vrow * (NS * 2) + (sw & 127), (char*)&Vs[0][0] + slot);
  }
  __syncthreads();

  int cur = 0;
  for (int kt = 0; kt < nkt; ++kt) {
    if (kt + 1 < nkt) {  // prefetch next tile into cur^1
      const size_t knext = (size_t)(kt + 1);
#pragma unroll
      for (int c = 0; c < 2; ++c) {
        const int chunk = wid * 2 + c;
        const int slot = chunk * 1024 + lane * 16;
        const int sw = slot ^ swz_lane;
        gload_lds16(Kg + knext * 8192 + sw, (char*)&Ks[cur ^ 1][0] + slot);
        const int vrow = slot >> 7;
        gload_lds16(Vg + (size_t)vrow * (NS * 2) + knext * 128 + (sw & 127),
                    (char*)&Vs[cur ^ 1][0] + slot);
      }
    }

    const bool diag = (kt == qt);
    const char* Kbuf = (const char*)&Ks[cur][0];
    const char* Vbuf = (const char*)&Vs[cur][0];

    // ---- S^T = K Q^T
    f32x4 sacc[4] = {};
    __builtin_amdgcn_s_setprio(1);
#pragma unroll
    for (int kk = 0; kk < 2; ++kk) {
#pragma unroll
      for (int n = 0; n < 4; ++n) {
        if (diag && n > wid) continue;
        const int off = ((n * 16 + l15) * 128 + kk * 64 + l4 * 16) ^ rswz;
        half8 kf = *(const half8*)(Kbuf + off);
        sacc[n] = __builtin_amdgcn_mfma_f32_16x16x32_f16(kf, qf[kk], sacc[n], 0, 0, 0);
      }
    }
    __builtin_amdgcn_s_setprio(0);

    // ---- online softmax (reduced VALU)
    float traw[16];
#pragma unroll
    for (int n = 0; n < 4; ++n)
#pragma unroll
      for (int r = 0; r < 4; ++r) {
        float v = sacc[n][r];
        if (diag) {
          const int ki = n * 16 + l4 * 4 + r;
          v = (ki > qloc) ? -3.0e38f : v;
        }
        traw[n * 4 + r] = v;
      }
    float mx = traw[0];
#pragma unroll
    for (int j = 1; j < 16; ++j) mx = fmaxf(mx, traw[j]);
    mx = fmaxf(mx, __shfl_xor(mx, 16, 64));
    mx = fmaxf(mx, __shfl_xor(mx, 32, 64));
    mx *= K1;
    const float mnew = fmaxf(mrun, mx);
    const float alpha = exp2_fast(mrun - mnew);
    mrun = mnew;
    float ps[16], rs = 0.f;
#pragma unroll
    for (int j = 0; j < 16; ++j) {
      ps[j] = exp2_fast(__builtin_fmaf(traw[j], K1, -mnew));
      rs += ps[j];
    }
    rs += __shfl_xor(rs, 16, 64);
    rs += __shfl_xor(rs, 32, 64);
    lrun = lrun * alpha + rs;
#pragma unroll
    for (int n = 0; n < 4; ++n) oacc[n] *= alpha;

    // ---- PV (V k-interleaved: one b128 per (c,n))
    __builtin_amdgcn_s_setprio(1);
#pragma unroll
    for (int c = 0; c < 2; ++c) {
      if (diag && c == 1 && wid < 2) continue;
      half8 pb;
#pragma unroll
      for (int q2 = 0; q2 < 4; ++q2) {
        fp16x2 pp = __builtin_amdgcn_cvt_pkrtz(ps[8 * c + 2 * q2],
                                               ps[8 * c + 2 * q2 + 1]);
        pb[2 * q2]     = (_Float16)pp[0];
        pb[2 * q2 + 1] = (_Float16)pp[1];
      }
#pragma unroll
      for (int n = 0; n < 4; ++n) {
        const int off = ((n * 16 + l15) * 128 + c * 64 + l4 * 16) ^ rswz;
        half8 va = *(const half8*)(Vbuf + off);
        oacc[n] = __builtin_amdgcn_mfma_f32_16x16x32_f16(va, pb, oacc[n], 0, 0, 0);
      }
    }
    __builtin_amdgcn_s_setprio(0);

    __syncthreads();
    cur ^= 1;
  }

  // ---- epilogue (registers + global only; no LDS)
  const int s = qt * 64 + wid * 16 + l15;
  const float invl = 1.0f / lrun;
#pragma unroll
  for (int n = 0; n < 4; ++n) {
    f32x4 ov = oacc[n] * invl;
    half4 o;
    o[0] = (_Float16)ov[0];
    o[1] = (_Float16)ov[1];
    o[2] = (_Float16)ov[2];
    o[3] = (_Float16)ov[3];
    *(half4*)&Ob[((size_t)(b * NS + s)) * ND + h * NHD + n * 16 + l4 * 4] = o;
  }
}

// ---------------------------------------------------------------- out proj
// BM=128, BN=64, BK=64 (swizzled). Grid (16,32) = 512 blocks.
__launch_bounds__(256, 2)
__global__ void proj_gemm(const _Float16* __restrict__ A,
                          const _Float16* __restrict__ W,
                          float* __restrict__ out) {
  __shared__ __align__(16) _Float16 As[128 * 64];
  __shared__ __align__(16) _Float16 Bs[64 * 64];
  const int tid = threadIdx.x, lane = tid & 63, wid = tid >> 6;
  const int l15 = lane & 15, l4 = lane >> 4;
  const int wr = wid >> 1, wc = wid & 1;
  const int brow = blockIdx.y * 128, bcol = blockIdx.x * 64;
  const int rswz = (l15 & 7) << 4;
  const int srb = tid >> 3;
  const int scb = (tid & 7) * 16;

  f32x4 acc[4][2] = {};
  for (int kt = 0; kt < ND / 64; ++kt) {
    const int k0 = kt * 64;
#pragma unroll
    for (int c = 0; c < 4; ++c) {
      const int r = c * 32 + srb;
      const int sb = scb ^ ((r & 7) << 4);
      gload_lds16((const char*)(A + (size_t)(brow + r) * ND + k0) + sb,
                  (char*)As + c * 4096 + tid * 16);
    }
#pragma unroll
    for (int c = 0; c < 2; ++c) {
      const int r = c * 32 + srb;
      const int sb = scb ^ ((r & 7) << 4);
      gload_lds16((const char*)(W + (size_t)(bcol + r) * ND + k0) + sb,
                  (char*)Bs + c * 4096 + tid * 16);
    }
    __syncthreads();
#pragma unroll
    for (int kk = 0; kk < 2; ++kk) {
      half8 af[4], bf[2];
#pragma unroll
      for (int m = 0; m < 4; ++m) {
        const int row = wr * 64 + m * 16 + l15;
        af[m] = *(const half8*)((const char*)As +
                 ((row * 128 + kk * 64 + l4 * 16) ^ rswz));
      }
#pragma unroll
      for (int n = 0; n < 2; ++n) {
        const int row = wc * 32 + n * 16 + l15;
        bf[n] = *(const half8*)((const char*)Bs +
                 ((row * 128 + kk * 64 + l4 * 16) ^ rswz));
      }
#pragma unroll
      for (int m = 0; m < 4; ++m)
#pragma unroll
        for (int n = 0; n < 2; ++n)
          acc[m][n] = __builtin_amdgcn_mfma_f32_16x16x32_f16(af[m], bf[n],
                                                             acc[m][n], 0, 0, 0);
    }
    __syncthreads();
  }
#pragma unroll
  for (int m = 0; m < 4; ++m)
#pragma unroll
    for (int n = 0; n < 2; ++n)
#pragma unroll
      for (int r = 0; r < 4; ++r)
        out[(size_t)(brow + wr * 64 + m * 16 + l4 * 4 + r) * ND
            + bcol + wc * 32 + n * 16 + l15] = acc[m][n][r];
}

// ---------------------------------------------------------------- launch
extern "C" void kernel_launch(void* const* d_in, const int* in_sizes, int n_in,
                              void* d_out, int out_size, void* d_ws, size_t ws_size,
                              hipStream_t stream) {
  const float* x  = (const float*)d_in[0];
  const float* wq = (const float*)d_in[2];
  const float* wk = (const float*)d_in[3];
  const float* wv = (const float*)d_in[4];
  const float* wo = (const float*)d_in[5];
  float* out = (float*)d_out;

  char* w = (char*)d_ws;
  _Float16* xb   = (_Float16*)(w);                    // 8 MB  [4096][1024]
  _Float16* wqb  = (_Float16*)(w + (8ull  << 20));    // 2 MB
  _Float16* wkb  = (_Float16*)(w + (10ull << 20));
  _Float16* wvb  = (_Float16*)(w + (12ull << 20));
  _Float16* wob  = (_Float16*)(w + (14ull << 20));
  _Float16* Qb   = (_Float16*)(w + (16ull << 20));    // 8 MB  [32][2048][64]
  _Float16* Kb   = (_Float16*)(w + (24ull << 20));    // 8 MB
  _Float16* Vt   = (_Float16*)(w + (32ull << 20));    // 8 MB  [32][64][2048] (k-interleaved)
  _Float16* Ob   = (_Float16*)(w + (40ull << 20));    // 8 MB  [4096][1024]
  float*    cosT = (float*)   (w + (48ull << 20));    // 256 KB [2048][32]
  float*    sinT = (float*)   (w + (48ull << 20) + (1ull << 18));

  dim3 blk(256);
  prep<<<4128, blk, 0, stream>>>(x, wq, wk, wv, wo, xb, wqb, wkb, wvb, wob,
                                 cosT, sinT);
  qkv_gemm<<<dim3(8, 32, 3), blk, 0, stream>>>(xb, wqb, wkb, wvb, Qb, Kb, Vt,
                                               cosT, sinT);
  flash_attn<<<1024, blk, 0, stream>>>(Qb, Kb, Vt, Ob);
  proj_gemm<<<dim3(16, 32), blk, 0, stream>>>(Ob, wob, out);
}